// Round 8
// baseline (360.805 us; speedup 1.0000x reference)
//
#include <hip/hip_runtime.h>

// Two-layer cached GCN. Round 14 = round-7 base (proven 321.3us) with:
// (a) DIAGNOSTIC: each agg split into two half-row dispatches (~32/28us).
//     The top-5 profile always shows only the slowest dispatch type, so
//     ~200us across 6 non-agg dispatches has been invisible. Splitting aggs
//     drops the visibility threshold to ~31us: the biggest unknown kernel
//     surfaces WITH its PMC counters. If only agg halves show, all others
//     are <31us (bound established, move to dispatch merging).
// (b) agg gather unroll x8 -> x16, four accumulator chains (MLP ladder:
//     x4->x8 gave +4% BW; latency-bound gather wants more outstanding loads).

#define BKT_SHIFT 7
#define BKT_NODES 128
#define CH 8192
#define MAXBKT 1024

typedef _Float16 half4v __attribute__((ext_vector_type(4)));
typedef _Float16 half8v __attribute__((ext_vector_type(8)));
typedef float float4v __attribute__((ext_vector_type(4)));

// ---------------- prep: W1/W2 -> fp16 transposed, zero bcnt + done-counter ----
__global__ __launch_bounds__(256) void k_prep(const float* __restrict__ W1,
                                              const float* __restrict__ W2,
                                              _Float16* __restrict__ wt1,
                                              _Float16* __restrict__ wt2,
                                              int* __restrict__ bcnt,
                                              int* __restrict__ dcnt, int nbkt) {
    int i = blockIdx.x * 256 + threadIdx.x;   // 0..32767
    if (i < 16384) {
        int k = i >> 7, c = i & 127;
        wt1[c * 128 + k] = (_Float16)W1[i];
    } else {
        int j = i - 16384;
        int k = j >> 7, c = j & 127;
        wt2[c * 128 + k] = (_Float16)W2[j];
    }
    if (i < nbkt) bcnt[i] = 0;
    if (i < 2) dcnt[i] = 0;
}

// ---------------- bucket histogram + last-block exclusive scan ----------------
__global__ __launch_bounds__(256) void k_bincount_scan(const int* __restrict__ dst,
                                                       int* __restrict__ bcnt,
                                                       int* __restrict__ bofs,
                                                       int* __restrict__ bcur,
                                                       int* __restrict__ dcnt,
                                                       int E, int nbkt, int nblocks) {
    __shared__ int sh[MAXBKT];
    const int t = threadIdx.x;
    for (int i = t; i < nbkt; i += 256) sh[i] = 0;
    __syncthreads();
    for (long long e = (long long)blockIdx.x * 256 + t; e < E;
         e += (long long)nblocks * 256)
        atomicAdd(&sh[dst[e] >> BKT_SHIFT], 1);
    __syncthreads();
    for (int i = t; i < nbkt; i += 256)
        if (sh[i]) atomicAdd(&bcnt[i], sh[i]);   // device-scope, coherent
    __threadfence();
    __syncthreads();
    __shared__ int last;
    if (t == 0) last = (atomicAdd(&dcnt[0], 1) == nblocks - 1);
    __syncthreads();
    if (!last) return;
    __threadfence();
    // last block: exclusive scan of bcnt[0..nbkt), 4/thread, coherent reads.
    int v[4];
    int s = 0;
    for (int k = 0; k < 4; k++) {
        int idx = t * 4 + k;
        v[k] = (idx < nbkt) ? atomicAdd(&bcnt[idx], 0) : 0;
        s += v[k];
    }
    __syncthreads();
    int x = s;
    sh[t] = x;
    __syncthreads();
    for (int o = 1; o < 256; o <<= 1) {
        int y = (t >= o) ? sh[t - o] : 0;
        __syncthreads();
        x += y;
        sh[t] = x;
        __syncthreads();
    }
    int run = x - s;
    for (int k = 0; k < 4; k++) {
        int idx = t * 4 + k;
        if (idx < nbkt) { bofs[idx] = run; bcur[idx] = run; }
        run += v[k];
    }
    if (t == 0) bofs[nbkt] = E;
}

// ---------------- bulk-reservation bin fill (proven CH=8192 config) ----------
__global__ __launch_bounds__(256) void k_binfill(const int* __restrict__ src,
                                                 const int* __restrict__ dst,
                                                 int* __restrict__ bcur,
                                                 unsigned* __restrict__ recs,
                                                 int E, int nbkt) {
    __shared__ unsigned stage[CH];          // 32 KB
    __shared__ unsigned short stageb[CH];   // 16 KB
    __shared__ int cnt[MAXBKT];             // 4 KB
    __shared__ int base[MAXBKT];            // 4 KB
    const int t = threadIdx.x;
    const long long c0 = (long long)blockIdx.x * CH;

    for (int i = t; i < nbkt; i += 256) cnt[i] = 0;
    __syncthreads();

    for (int k = 0; k < CH / 256; k++) {
        int i = k * 256 + t;
        long long e = c0 + i;
        if (e < E) {
            int d = dst[e];
            int b = d >> BKT_SHIFT;
            stage[i] = ((unsigned)(d & (BKT_NODES - 1)) << 17) | (unsigned)src[e];
            stageb[i] = (unsigned short)b;
            atomicAdd(&cnt[b], 1);
        }
    }
    __syncthreads();

    for (int i = t; i < nbkt; i += 256) {
        int c = cnt[i];
        base[i] = c ? atomicAdd(&bcur[i], c) : 0;
        cnt[i] = 0;
    }
    __syncthreads();

    for (int k = 0; k < CH / 256; k++) {
        int i = k * 256 + t;
        if (c0 + i < E) {
            int b = stageb[i];
            int p = base[b] + atomicAdd(&cnt[b], 1);
            recs[p] = stage[i];
        }
    }
}

// ---------------- fused deg + scan + CSR fill ----------------
__global__ __launch_bounds__(256) void k_fill_all(const unsigned* __restrict__ recs,
                                                  const int* __restrict__ bofs,
                                                  float* __restrict__ dinv,
                                                  int* __restrict__ ofs,
                                                  int* __restrict__ col,
                                                  int n, int E) {
    __shared__ int cnt[BKT_NODES];
    __shared__ int sc[BKT_NODES];
    const int b = blockIdx.x, t = threadIdx.x;
    const int beg = bofs[b], end = bofs[b + 1];

    if (t < BKT_NODES) cnt[t] = 0;
    __syncthreads();
    for (int j = beg + t; j < end; j += 256)
        atomicAdd(&cnt[recs[j] >> 17], 1);
    __syncthreads();

    int v = 0, x = 0;
    if (t < BKT_NODES) { v = cnt[t]; x = v; sc[t] = x; }
    __syncthreads();
    for (int o = 1; o < BKT_NODES; o <<= 1) {
        int y = (t >= o && t < BKT_NODES) ? sc[t - o] : 0;
        __syncthreads();
        if (t < BKT_NODES) { x += y; sc[t] = x; }
        __syncthreads();
    }

    const int d0 = b << BKT_SHIFT;
    if (t < BKT_NODES) {
        int off = beg + x - v;
        int node = d0 + t;
        if (node < n) {
            ofs[node] = off;
            dinv[node] = rsqrtf((float)v + 1.0f);
        }
        cnt[t] = off;   // becomes cur
    }
    if (b == 0 && t == 0) ofs[n] = E;
    __syncthreads();

    for (int j = beg + t; j < end; j += 256) {
        unsigned r = recs[j];
        int p = atomicAdd(&cnt[r >> 17], 1);
        col[p] = (int)(r & 0x1FFFF);
    }
}

// ---------------- MFMA GEMM: ts[N x 128](fp16) = dinv[row] * (in @ W) ------
// A fragments straight from global (read-once); only W in LDS; 4 blocks/CU.
template <int IN_HALF>
__global__ __launch_bounds__(256, 4) void k_gemm_mfma(const void* __restrict__ inp,
                                                      const _Float16* __restrict__ Wt,
                                                      const float* __restrict__ dinv,
                                                      _Float16* __restrict__ out, int n) {
    __shared__ _Float16 Bl[128][136];  // 34.8 KB
    const int t = threadIdx.x;
    const int row0 = blockIdx.x * 64;

    for (int i = t; i < 128 * 16; i += 256) {
        int r = i >> 4, c8 = i & 15;
        *(half8v*)&Bl[r][c8 * 8] = *(const half8v*)&Wt[r * 128 + c8 * 8];
    }
    __syncthreads();

    const int wave = t >> 6;
    const int lane = t & 63;
    const int m0 = wave * 16;
    const int ml = lane & 15;
    const int quad = lane >> 4;

    int r = row0 + m0 + ml;
    if (r >= n) r = n - 1;   // clamp: OOB rows compute garbage, never stored

    float4v acc[8] = {};
#pragma unroll
    for (int kc = 0; kc < 4; kc++) {
        half8v a;
        if (IN_HALF) {
            a = *(const half8v*)((const _Float16*)inp + (size_t)r * 128 + kc * 32 + quad * 8);
        } else {
            const float* ap = (const float*)inp + (size_t)r * 128 + kc * 32 + quad * 8;
            float4v v0 = *(const float4v*)ap;
            float4v v1 = *(const float4v*)(ap + 4);
#pragma unroll
            for (int k = 0; k < 4; k++) {
                a[k] = (_Float16)v0[k];
                a[4 + k] = (_Float16)v1[k];
            }
        }
#pragma unroll
        for (int nt = 0; nt < 8; nt++) {
            half8v bfr = *(const half8v*)&Bl[nt * 16 + ml][kc * 32 + quad * 8];
            acc[nt] = __builtin_amdgcn_mfma_f32_16x16x32_f16(a, bfr, acc[nt], 0, 0, 0);
        }
    }

    int nr = n - row0;
    if (nr > 64) nr = 64;
#pragma unroll
    for (int reg = 0; reg < 4; reg++) {
        int rr = m0 + quad * 4 + reg;
        if (rr < nr) {
            float dv = dinv[row0 + rr];
#pragma unroll
            for (int nt = 0; nt < 8; nt++)
                out[(size_t)(row0 + rr) * 128 + nt * 16 + ml] =
                    (_Float16)(acc[nt][reg] * dv);
        }
    }
}

// ---------------- CSR aggregation (32-lane, row-range, unroll x16) ----------
// Processes rows [r0, r1). OUT_HALF=1: out = relu(b + dinv*acc) as fp16.
template <int OUT_HALF>
__global__ __launch_bounds__(256) void k_agg_csr(const int* __restrict__ ofs,
                                                 const int* __restrict__ col,
                                                 const float* __restrict__ dinv,
                                                 const half4v* __restrict__ ts,
                                                 const float* __restrict__ bias,
                                                 void* __restrict__ outp,
                                                 int r0, int r1) {
    int gid = blockIdx.x * 256 + threadIdx.x;
    int row = r0 + (gid >> 5);
    int lane = gid & 31;
    if (row >= r1) return;

    float dd = dinv[row];
    int beg = ofs[row];
    int end = ofs[row + 1];

    half4v sv = ts[(size_t)row * 32 + lane];
    float4 acc  = make_float4((float)sv[0], (float)sv[1], (float)sv[2], (float)sv[3]);
    float4 acc2 = make_float4(0.f, 0.f, 0.f, 0.f);
    float4 acc3 = make_float4(0.f, 0.f, 0.f, 0.f);
    float4 acc4 = make_float4(0.f, 0.f, 0.f, 0.f);

    int j = beg;
    for (; j + 15 < end; j += 16) {
        int s0 = col[j],      s1 = col[j + 1],  s2 = col[j + 2],  s3 = col[j + 3];
        int s4 = col[j + 4],  s5 = col[j + 5],  s6 = col[j + 6],  s7 = col[j + 7];
        int s8 = col[j + 8],  s9 = col[j + 9],  sa = col[j + 10], sb = col[j + 11];
        int sc = col[j + 12], sd = col[j + 13], se = col[j + 14], sf = col[j + 15];
        half4v v0 = ts[(size_t)s0 * 32 + lane];
        half4v v1 = ts[(size_t)s1 * 32 + lane];
        half4v v2 = ts[(size_t)s2 * 32 + lane];
        half4v v3 = ts[(size_t)s3 * 32 + lane];
        half4v v4 = ts[(size_t)s4 * 32 + lane];
        half4v v5 = ts[(size_t)s5 * 32 + lane];
        half4v v6 = ts[(size_t)s6 * 32 + lane];
        half4v v7 = ts[(size_t)s7 * 32 + lane];
        half4v v8 = ts[(size_t)s8 * 32 + lane];
        half4v v9 = ts[(size_t)s9 * 32 + lane];
        half4v va = ts[(size_t)sa * 32 + lane];
        half4v vb = ts[(size_t)sb * 32 + lane];
        half4v vc = ts[(size_t)sc * 32 + lane];
        half4v vd = ts[(size_t)sd * 32 + lane];
        half4v ve = ts[(size_t)se * 32 + lane];
        half4v vf = ts[(size_t)sf * 32 + lane];
        acc.x  += (float)v0[0] + (float)v1[0] + (float)v2[0] + (float)v3[0];
        acc.y  += (float)v0[1] + (float)v1[1] + (float)v2[1] + (float)v3[1];
        acc.z  += (float)v0[2] + (float)v1[2] + (float)v2[2] + (float)v3[2];
        acc.w  += (float)v0[3] + (float)v1[3] + (float)v2[3] + (float)v3[3];
        acc2.x += (float)v4[0] + (float)v5[0] + (float)v6[0] + (float)v7[0];
        acc2.y += (float)v4[1] + (float)v5[1] + (float)v6[1] + (float)v7[1];
        acc2.z += (float)v4[2] + (float)v5[2] + (float)v6[2] + (float)v7[2];
        acc2.w += (float)v4[3] + (float)v5[3] + (float)v6[3] + (float)v7[3];
        acc3.x += (float)v8[0] + (float)v9[0] + (float)va[0] + (float)vb[0];
        acc3.y += (float)v8[1] + (float)v9[1] + (float)va[1] + (float)vb[1];
        acc3.z += (float)v8[2] + (float)v9[2] + (float)va[2] + (float)vb[2];
        acc3.w += (float)v8[3] + (float)v9[3] + (float)va[3] + (float)vb[3];
        acc4.x += (float)vc[0] + (float)vd[0] + (float)ve[0] + (float)vf[0];
        acc4.y += (float)vc[1] + (float)vd[1] + (float)ve[1] + (float)vf[1];
        acc4.z += (float)vc[2] + (float)vd[2] + (float)ve[2] + (float)vf[2];
        acc4.w += (float)vc[3] + (float)vd[3] + (float)ve[3] + (float)vf[3];
    }
    for (; j + 3 < end; j += 4) {
        int s0 = col[j], s1 = col[j + 1], s2 = col[j + 2], s3 = col[j + 3];
        half4v v0 = ts[(size_t)s0 * 32 + lane];
        half4v v1 = ts[(size_t)s1 * 32 + lane];
        half4v v2 = ts[(size_t)s2 * 32 + lane];
        half4v v3 = ts[(size_t)s3 * 32 + lane];
        acc.x += (float)v0[0] + (float)v1[0] + (float)v2[0] + (float)v3[0];
        acc.y += (float)v0[1] + (float)v1[1] + (float)v2[1] + (float)v3[1];
        acc.z += (float)v0[2] + (float)v1[2] + (float)v2[2] + (float)v3[2];
        acc.w += (float)v0[3] + (float)v1[3] + (float)v2[3] + (float)v3[3];
    }
    for (; j < end; j++) {
        half4v v = ts[(size_t)col[j] * 32 + lane];
        acc.x += (float)v[0];
        acc.y += (float)v[1];
        acc.z += (float)v[2];
        acc.w += (float)v[3];
    }
    acc.x += acc2.x + acc3.x + acc4.x;
    acc.y += acc2.y + acc3.y + acc4.y;
    acc.z += acc2.z + acc3.z + acc4.z;
    acc.w += acc2.w + acc3.w + acc4.w;

    float4 bv = *(const float4*)&bias[lane * 4];
    if (OUT_HALF) {
        half4v hv;
        hv[0] = (_Float16)fmaxf(bv.x + dd * acc.x, 0.f);
        hv[1] = (_Float16)fmaxf(bv.y + dd * acc.y, 0.f);
        hv[2] = (_Float16)fmaxf(bv.z + dd * acc.z, 0.f);
        hv[3] = (_Float16)fmaxf(bv.w + dd * acc.w, 0.f);
        ((half4v*)outp)[(size_t)row * 32 + lane] = hv;
    } else {
        float4 o;
        o.x = bv.x + dd * acc.x;
        o.y = bv.y + dd * acc.y;
        o.z = bv.z + dd * acc.z;
        o.w = bv.w + dd * acc.w;
        *(float4*)&((float*)outp)[(size_t)row * 128 + lane * 4] = o;
    }
}

extern "C" void kernel_launch(void* const* d_in, const int* in_sizes, int n_in,
                              void* d_out, int out_size, void* d_ws, size_t ws_size,
                              hipStream_t stream) {
    const int N = in_sizes[0] / 128;
    const int E = in_sizes[1] / 2;
    const float* x  = (const float*)d_in[0];
    const int*   ei = (const int*)d_in[1];
    const float* W1 = (const float*)d_in[2];
    const float* b1 = (const float*)d_in[3];
    const float* W2 = (const float*)d_in[4];
    const float* b2 = (const float*)d_in[5];

    const int* src = ei;
    const int* dst = ei + E;

    const int NBKT = (N + BKT_NODES - 1) / BKT_NODES;

    // ---- workspace layout ----
    _Float16* t    = (_Float16*)d_ws;            // N*128 (ts, reused per layer)
    _Float16* wt1  = t + (size_t)N * 128;        // 16384
    _Float16* wt2  = wt1 + 16384;                // 16384
    float*    dinv = (float*)(wt2 + 16384);      // N
    int*      ofs  = (int*)(dinv + N);           // N+1
    unsigned* recs = (unsigned*)(ofs + ((N + 2 + 255) & ~255)); // E
    int*      col  = (int*)(recs + E);           // E
    int*      bofs = col + E;                    // NBKT+1
    int*      bcur = bofs + NBKT + 1;            // NBKT
    int*      bcnt = bcur + NBKT;                // NBKT
    int*      dcnt = bcnt + NBKT;                // 2 (done counters)

    // layer-1 hidden (fp16, relu applied) in front half of d_out;
    // final fp32 out overwrites d_out afterwards (h16 dead by then).
    _Float16* h16 = (_Float16*)d_out;
    float*    out = (float*)d_out;

    const int nb_g = (N + 63) / 64;
    const int nb_c = (int)(((long long)E + CH - 1) / CH);
    const int Nh   = N / 2;
    const int nb_a1 = (int)(((long long)Nh * 32 + 255) / 256);
    const int nb_a2 = (int)(((long long)(N - Nh) * 32 + 255) / 256);

    // ---- prep + binning + fused CSR build (4 dispatches) ----
    k_prep<<<128, 256, 0, stream>>>(W1, W2, wt1, wt2, bcnt, dcnt, NBKT);
    k_bincount_scan<<<256, 256, 0, stream>>>(dst, bcnt, bofs, bcur, dcnt, E, NBKT, 256);
    k_binfill<<<nb_c, 256, 0, stream>>>(src, dst, bcur, recs, E, NBKT);
    k_fill_all<<<NBKT, 256, 0, stream>>>(recs, bofs, dinv, ofs, col, N, E);

    // ---- layer 1: ts = dinv*(x@W1); h16 = relu(b1 + dinv*(ts[d] + sum ts[col])) ----
    k_gemm_mfma<0><<<nb_g, 256, 0, stream>>>(x, wt1, dinv, t, N);
    k_agg_csr<1><<<nb_a1, 256, 0, stream>>>(ofs, col, dinv, (const half4v*)t, b1, h16, 0, Nh);
    k_agg_csr<1><<<nb_a2, 256, 0, stream>>>(ofs, col, dinv, (const half4v*)t, b1, h16, Nh, N);

    // ---- layer 2: ts = dinv*(h16@W2); out = b2 + dinv*(ts[d] + sum ts[col]) ----
    k_gemm_mfma<1><<<nb_g, 256, 0, stream>>>(h16, wt2, dinv, t, N);
    k_agg_csr<0><<<nb_a1, 256, 0, stream>>>(ofs, col, dinv, (const half4v*)t, b2, out, 0, Nh);
    k_agg_csr<0><<<nb_a2, 256, 0, stream>>>(ofs, col, dinv, (const half4v*)t, b2, out, Nh, N);
}

// Round 9
// 359.711 us; speedup vs baseline: 1.0030x; 1.0030x over previous
//
#include <hip/hip_runtime.h>

// Two-layer cached GCN. Round 15:
// (a) agg reverted to round-7-proven form (x8 unroll, unsplit, 64.3us @
//     3.8TB/s). Round-8's half-split cost ~11us/dispatch ramp+drain
//     (occupancy 70->39%) — reverted. Yield: no non-agg kernel >43us.
// (b) gemm: LDS-free. W (32KB) is L2-resident after block 0; staging it
//     into LDS per block cost a 34.8KB occupancy cap (4 blocks/CU), a
//     full-block barrier, and stage->compute serialization at only 6
//     blocks/CU TLP. Now B-fragments load straight from global (16 rows x
//     64B contiguous per wave-load, fully coalesced) -> no LDS, no barrier,
//     VGPR-bound occupancy, latency hidden. A/B vs round 7 attributes any
//     delta purely to the gemm change (agg byte-identical).

#define BKT_SHIFT 7
#define BKT_NODES 128
#define CH 8192
#define MAXBKT 1024

typedef _Float16 half4v __attribute__((ext_vector_type(4)));
typedef _Float16 half8v __attribute__((ext_vector_type(8)));
typedef float float4v __attribute__((ext_vector_type(4)));

// ---------------- prep: W1/W2 -> fp16 transposed, zero bcnt + done-counter ----
__global__ __launch_bounds__(256) void k_prep(const float* __restrict__ W1,
                                              const float* __restrict__ W2,
                                              _Float16* __restrict__ wt1,
                                              _Float16* __restrict__ wt2,
                                              int* __restrict__ bcnt,
                                              int* __restrict__ dcnt, int nbkt) {
    int i = blockIdx.x * 256 + threadIdx.x;   // 0..32767
    if (i < 16384) {
        int k = i >> 7, c = i & 127;
        wt1[c * 128 + k] = (_Float16)W1[i];
    } else {
        int j = i - 16384;
        int k = j >> 7, c = j & 127;
        wt2[c * 128 + k] = (_Float16)W2[j];
    }
    if (i < nbkt) bcnt[i] = 0;
    if (i < 2) dcnt[i] = 0;
}

// ---------------- bucket histogram + last-block exclusive scan ----------------
__global__ __launch_bounds__(256) void k_bincount_scan(const int* __restrict__ dst,
                                                       int* __restrict__ bcnt,
                                                       int* __restrict__ bofs,
                                                       int* __restrict__ bcur,
                                                       int* __restrict__ dcnt,
                                                       int E, int nbkt, int nblocks) {
    __shared__ int sh[MAXBKT];
    const int t = threadIdx.x;
    for (int i = t; i < nbkt; i += 256) sh[i] = 0;
    __syncthreads();
    for (long long e = (long long)blockIdx.x * 256 + t; e < E;
         e += (long long)nblocks * 256)
        atomicAdd(&sh[dst[e] >> BKT_SHIFT], 1);
    __syncthreads();
    for (int i = t; i < nbkt; i += 256)
        if (sh[i]) atomicAdd(&bcnt[i], sh[i]);   // device-scope, coherent
    __threadfence();
    __syncthreads();
    __shared__ int last;
    if (t == 0) last = (atomicAdd(&dcnt[0], 1) == nblocks - 1);
    __syncthreads();
    if (!last) return;
    __threadfence();
    // last block: exclusive scan of bcnt[0..nbkt), 4/thread, coherent reads.
    int v[4];
    int s = 0;
    for (int k = 0; k < 4; k++) {
        int idx = t * 4 + k;
        v[k] = (idx < nbkt) ? atomicAdd(&bcnt[idx], 0) : 0;
        s += v[k];
    }
    __syncthreads();
    int x = s;
    sh[t] = x;
    __syncthreads();
    for (int o = 1; o < 256; o <<= 1) {
        int y = (t >= o) ? sh[t - o] : 0;
        __syncthreads();
        x += y;
        sh[t] = x;
        __syncthreads();
    }
    int run = x - s;
    for (int k = 0; k < 4; k++) {
        int idx = t * 4 + k;
        if (idx < nbkt) { bofs[idx] = run; bcur[idx] = run; }
        run += v[k];
    }
    if (t == 0) bofs[nbkt] = E;
}

// ---------------- bulk-reservation bin fill (proven CH=8192 config) ----------
__global__ __launch_bounds__(256) void k_binfill(const int* __restrict__ src,
                                                 const int* __restrict__ dst,
                                                 int* __restrict__ bcur,
                                                 unsigned* __restrict__ recs,
                                                 int E, int nbkt) {
    __shared__ unsigned stage[CH];          // 32 KB
    __shared__ unsigned short stageb[CH];   // 16 KB
    __shared__ int cnt[MAXBKT];             // 4 KB
    __shared__ int base[MAXBKT];            // 4 KB
    const int t = threadIdx.x;
    const long long c0 = (long long)blockIdx.x * CH;

    for (int i = t; i < nbkt; i += 256) cnt[i] = 0;
    __syncthreads();

    for (int k = 0; k < CH / 256; k++) {
        int i = k * 256 + t;
        long long e = c0 + i;
        if (e < E) {
            int d = dst[e];
            int b = d >> BKT_SHIFT;
            stage[i] = ((unsigned)(d & (BKT_NODES - 1)) << 17) | (unsigned)src[e];
            stageb[i] = (unsigned short)b;
            atomicAdd(&cnt[b], 1);
        }
    }
    __syncthreads();

    for (int i = t; i < nbkt; i += 256) {
        int c = cnt[i];
        base[i] = c ? atomicAdd(&bcur[i], c) : 0;
        cnt[i] = 0;
    }
    __syncthreads();

    for (int k = 0; k < CH / 256; k++) {
        int i = k * 256 + t;
        if (c0 + i < E) {
            int b = stageb[i];
            int p = base[b] + atomicAdd(&cnt[b], 1);
            recs[p] = stage[i];
        }
    }
}

// ---------------- fused deg + scan + CSR fill ----------------
__global__ __launch_bounds__(256) void k_fill_all(const unsigned* __restrict__ recs,
                                                  const int* __restrict__ bofs,
                                                  float* __restrict__ dinv,
                                                  int* __restrict__ ofs,
                                                  int* __restrict__ col,
                                                  int n, int E) {
    __shared__ int cnt[BKT_NODES];
    __shared__ int sc[BKT_NODES];
    const int b = blockIdx.x, t = threadIdx.x;
    const int beg = bofs[b], end = bofs[b + 1];

    if (t < BKT_NODES) cnt[t] = 0;
    __syncthreads();
    for (int j = beg + t; j < end; j += 256)
        atomicAdd(&cnt[recs[j] >> 17], 1);
    __syncthreads();

    int v = 0, x = 0;
    if (t < BKT_NODES) { v = cnt[t]; x = v; sc[t] = x; }
    __syncthreads();
    for (int o = 1; o < BKT_NODES; o <<= 1) {
        int y = (t >= o && t < BKT_NODES) ? sc[t - o] : 0;
        __syncthreads();
        if (t < BKT_NODES) { x += y; sc[t] = x; }
        __syncthreads();
    }

    const int d0 = b << BKT_SHIFT;
    if (t < BKT_NODES) {
        int off = beg + x - v;
        int node = d0 + t;
        if (node < n) {
            ofs[node] = off;
            dinv[node] = rsqrtf((float)v + 1.0f);
        }
        cnt[t] = off;   // becomes cur
    }
    if (b == 0 && t == 0) ofs[n] = E;
    __syncthreads();

    for (int j = beg + t; j < end; j += 256) {
        unsigned r = recs[j];
        int p = atomicAdd(&cnt[r >> 17], 1);
        col[p] = (int)(r & 0x1FFFF);
    }
}

// ---------------- MFMA GEMM (LDS-free): ts[N x 128](fp16) = dinv*(in @ W) --
// B-fragments load straight from global Wt (L2-resident 32KB): per-wave
// load = rows nt*16..+15 x 64B contiguous, fully coalesced. No LDS, no
// barrier; occupancy VGPR-bound; A read-once from global.
template <int IN_HALF>
__global__ __launch_bounds__(256) void k_gemm_mfma(const void* __restrict__ inp,
                                                   const _Float16* __restrict__ Wt,
                                                   const float* __restrict__ dinv,
                                                   _Float16* __restrict__ out, int n) {
    const int t = threadIdx.x;
    const int row0 = blockIdx.x * 64;
    const int wave = t >> 6;
    const int lane = t & 63;
    const int m0 = wave * 16;
    const int ml = lane & 15;
    const int quad = lane >> 4;

    int r = row0 + m0 + ml;
    if (r >= n) r = n - 1;   // clamp: OOB rows compute garbage, never stored

    float4v acc[8] = {};
#pragma unroll
    for (int kc = 0; kc < 4; kc++) {
        half8v a;
        if (IN_HALF) {
            a = *(const half8v*)((const _Float16*)inp + (size_t)r * 128 + kc * 32 + quad * 8);
        } else {
            const float* ap = (const float*)inp + (size_t)r * 128 + kc * 32 + quad * 8;
            float4v v0 = *(const float4v*)ap;
            float4v v1 = *(const float4v*)(ap + 4);
#pragma unroll
            for (int k = 0; k < 4; k++) {
                a[k] = (_Float16)v0[k];
                a[4 + k] = (_Float16)v1[k];
            }
        }
#pragma unroll
        for (int nt = 0; nt < 8; nt++) {
            half8v bfr = *(const half8v*)&Wt[(size_t)(nt * 16 + ml) * 128 + kc * 32 + quad * 8];
            acc[nt] = __builtin_amdgcn_mfma_f32_16x16x32_f16(a, bfr, acc[nt], 0, 0, 0);
        }
    }

    int nr = n - row0;
    if (nr > 64) nr = 64;
#pragma unroll
    for (int reg = 0; reg < 4; reg++) {
        int rr = m0 + quad * 4 + reg;
        if (rr < nr) {
            float dv = dinv[row0 + rr];
#pragma unroll
            for (int nt = 0; nt < 8; nt++)
                out[(size_t)(row0 + rr) * 128 + nt * 16 + ml] =
                    (_Float16)(acc[nt][reg] * dv);
        }
    }
}

// ---------------- CSR aggregation (round-7-proven: 32-lane, unroll x8) ------
template <int OUT_HALF>
__global__ __launch_bounds__(256) void k_agg_csr(const int* __restrict__ ofs,
                                                 const int* __restrict__ col,
                                                 const float* __restrict__ dinv,
                                                 const half4v* __restrict__ ts,
                                                 const float* __restrict__ bias,
                                                 void* __restrict__ outp, int n) {
    int gid = blockIdx.x * 256 + threadIdx.x;
    int row = gid >> 5;
    int lane = gid & 31;
    if (row >= n) return;

    float dd = dinv[row];
    int beg = ofs[row];
    int end = ofs[row + 1];

    half4v sv = ts[(size_t)row * 32 + lane];
    float4 acc = make_float4((float)sv[0], (float)sv[1], (float)sv[2], (float)sv[3]);
    float4 acc2 = make_float4(0.f, 0.f, 0.f, 0.f);

    int j = beg;
    for (; j + 7 < end; j += 8) {
        int s0 = col[j],     s1 = col[j + 1], s2 = col[j + 2], s3 = col[j + 3];
        int s4 = col[j + 4], s5 = col[j + 5], s6 = col[j + 6], s7 = col[j + 7];
        half4v v0 = ts[(size_t)s0 * 32 + lane];
        half4v v1 = ts[(size_t)s1 * 32 + lane];
        half4v v2 = ts[(size_t)s2 * 32 + lane];
        half4v v3 = ts[(size_t)s3 * 32 + lane];
        half4v v4 = ts[(size_t)s4 * 32 + lane];
        half4v v5 = ts[(size_t)s5 * 32 + lane];
        half4v v6 = ts[(size_t)s6 * 32 + lane];
        half4v v7 = ts[(size_t)s7 * 32 + lane];
        acc.x  += (float)v0[0] + (float)v1[0] + (float)v2[0] + (float)v3[0];
        acc.y  += (float)v0[1] + (float)v1[1] + (float)v2[1] + (float)v3[1];
        acc.z  += (float)v0[2] + (float)v1[2] + (float)v2[2] + (float)v3[2];
        acc.w  += (float)v0[3] + (float)v1[3] + (float)v2[3] + (float)v3[3];
        acc2.x += (float)v4[0] + (float)v5[0] + (float)v6[0] + (float)v7[0];
        acc2.y += (float)v4[1] + (float)v5[1] + (float)v6[1] + (float)v7[1];
        acc2.z += (float)v4[2] + (float)v5[2] + (float)v6[2] + (float)v7[2];
        acc2.w += (float)v4[3] + (float)v5[3] + (float)v6[3] + (float)v7[3];
    }
    for (; j + 3 < end; j += 4) {
        int s0 = col[j], s1 = col[j + 1], s2 = col[j + 2], s3 = col[j + 3];
        half4v v0 = ts[(size_t)s0 * 32 + lane];
        half4v v1 = ts[(size_t)s1 * 32 + lane];
        half4v v2 = ts[(size_t)s2 * 32 + lane];
        half4v v3 = ts[(size_t)s3 * 32 + lane];
        acc.x += (float)v0[0] + (float)v1[0] + (float)v2[0] + (float)v3[0];
        acc.y += (float)v0[1] + (float)v1[1] + (float)v2[1] + (float)v3[1];
        acc.z += (float)v0[2] + (float)v1[2] + (float)v2[2] + (float)v3[2];
        acc.w += (float)v0[3] + (float)v1[3] + (float)v2[3] + (float)v3[3];
    }
    for (; j < end; j++) {
        half4v v = ts[(size_t)col[j] * 32 + lane];
        acc.x += (float)v[0];
        acc.y += (float)v[1];
        acc.z += (float)v[2];
        acc.w += (float)v[3];
    }
    acc.x += acc2.x; acc.y += acc2.y; acc.z += acc2.z; acc.w += acc2.w;

    float4 bv = *(const float4*)&bias[lane * 4];
    if (OUT_HALF) {
        half4v hv;
        hv[0] = (_Float16)fmaxf(bv.x + dd * acc.x, 0.f);
        hv[1] = (_Float16)fmaxf(bv.y + dd * acc.y, 0.f);
        hv[2] = (_Float16)fmaxf(bv.z + dd * acc.z, 0.f);
        hv[3] = (_Float16)fmaxf(bv.w + dd * acc.w, 0.f);
        ((half4v*)outp)[(size_t)row * 32 + lane] = hv;
    } else {
        float4 o;
        o.x = bv.x + dd * acc.x;
        o.y = bv.y + dd * acc.y;
        o.z = bv.z + dd * acc.z;
        o.w = bv.w + dd * acc.w;
        *(float4*)&((float*)outp)[(size_t)row * 128 + lane * 4] = o;
    }
}

extern "C" void kernel_launch(void* const* d_in, const int* in_sizes, int n_in,
                              void* d_out, int out_size, void* d_ws, size_t ws_size,
                              hipStream_t stream) {
    const int N = in_sizes[0] / 128;
    const int E = in_sizes[1] / 2;
    const float* x  = (const float*)d_in[0];
    const int*   ei = (const int*)d_in[1];
    const float* W1 = (const float*)d_in[2];
    const float* b1 = (const float*)d_in[3];
    const float* W2 = (const float*)d_in[4];
    const float* b2 = (const float*)d_in[5];

    const int* src = ei;
    const int* dst = ei + E;

    const int NBKT = (N + BKT_NODES - 1) / BKT_NODES;

    // ---- workspace layout ----
    _Float16* t    = (_Float16*)d_ws;            // N*128 (ts, reused per layer)
    _Float16* wt1  = t + (size_t)N * 128;        // 16384
    _Float16* wt2  = wt1 + 16384;                // 16384
    float*    dinv = (float*)(wt2 + 16384);      // N
    int*      ofs  = (int*)(dinv + N);           // N+1
    unsigned* recs = (unsigned*)(ofs + ((N + 2 + 255) & ~255)); // E
    int*      col  = (int*)(recs + E);           // E
    int*      bofs = col + E;                    // NBKT+1
    int*      bcur = bofs + NBKT + 1;            // NBKT
    int*      bcnt = bcur + NBKT;                // NBKT
    int*      dcnt = bcnt + NBKT;                // 2 (done counters)

    // layer-1 hidden (fp16, relu applied) in front half of d_out;
    // final fp32 out overwrites d_out afterwards (h16 dead by then).
    _Float16* h16 = (_Float16*)d_out;
    float*    out = (float*)d_out;

    const int nb_g = (N + 63) / 64;
    const int nb_a = (int)(((long long)N * 32 + 255) / 256);
    const int nb_c = (int)(((long long)E + CH - 1) / CH);

    // ---- prep + binning + fused CSR build (4 dispatches) ----
    k_prep<<<128, 256, 0, stream>>>(W1, W2, wt1, wt2, bcnt, dcnt, NBKT);
    k_bincount_scan<<<256, 256, 0, stream>>>(dst, bcnt, bofs, bcur, dcnt, E, NBKT, 256);
    k_binfill<<<nb_c, 256, 0, stream>>>(src, dst, bcur, recs, E, NBKT);
    k_fill_all<<<NBKT, 256, 0, stream>>>(recs, bofs, dinv, ofs, col, N, E);

    // ---- layer 1: ts = dinv*(x@W1); h16 = relu(b1 + dinv*(ts[d] + sum ts[col])) ----
    k_gemm_mfma<0><<<nb_g, 256, 0, stream>>>(x, wt1, dinv, t, N);
    k_agg_csr<1><<<nb_a, 256, 0, stream>>>(ofs, col, dinv, (const half4v*)t, b1, h16, N);

    // ---- layer 2: ts = dinv*(h16@W2); out = b2 + dinv*(ts[d] + sum ts[col]) ----
    k_gemm_mfma<1><<<nb_g, 256, 0, stream>>>(h16, wt2, dinv, t, N);
    k_agg_csr<0><<<nb_a, 256, 0, stream>>>(ofs, col, dinv, (const half4v*)t, b2, out, N);
}

// Round 10
// 345.004 us; speedup vs baseline: 1.0458x; 1.0426x over previous
//
#include <hip/hip_runtime.h>

// Two-layer cached GCN. Round 16 = round-7 proven kernel (321.3us: x8-unroll
// agg + W-in-LDS gemm + collapsed build) with two isolated changes:
// (a) binfill CH 8192 -> 2048: was 196 blocks = 0.77 blocks/CU (77% of CUs
//     idle) with 56KB LDS; now 782 blocks (3/CU), 20KB LDS. The single most
//     under-parallelized kernel in the chain.
// (b) k_prep folded into k_bincount_scan (blocks 0..127 transpose W first;
//     bcnt/dcnt zeroed via one hipMemsetAsync) — one fewer dispatch.
// Round-9 lesson logged: LDS-free gemm cost +38us (L1 operand loads lose to
// ds_read_b128); W staging is load-bearing. Reverted.

#define BKT_SHIFT 7
#define BKT_NODES 128
#define CH 2048
#define MAXBKT 1024

typedef _Float16 half4v __attribute__((ext_vector_type(4)));
typedef _Float16 half8v __attribute__((ext_vector_type(8)));
typedef float float4v __attribute__((ext_vector_type(4)));

// ---------------- bucket histogram + last-block exclusive scan ----------------
// Blocks 0..127 additionally transpose W1/W2 -> fp16 wt1/wt2 (consumed only
// by gemm dispatches, 3+ kernels later — no ordering hazard).
__global__ __launch_bounds__(256) void k_bincount_scan(const int* __restrict__ dst,
                                                       const float* __restrict__ W1,
                                                       const float* __restrict__ W2,
                                                       _Float16* __restrict__ wt1,
                                                       _Float16* __restrict__ wt2,
                                                       int* __restrict__ bcnt,
                                                       int* __restrict__ bofs,
                                                       int* __restrict__ bcur,
                                                       int* __restrict__ dcnt,
                                                       int E, int nbkt, int nblocks) {
    __shared__ int sh[MAXBKT];
    const int t = threadIdx.x;
    {   // folded W transpose (one element per thread for blocks 0..127)
        int gidx = blockIdx.x * 256 + t;
        if (gidx < 16384) {
            int k = gidx >> 7, c = gidx & 127;
            wt1[c * 128 + k] = (_Float16)W1[gidx];
        } else if (gidx < 32768) {
            int j = gidx - 16384;
            int k = j >> 7, c = j & 127;
            wt2[c * 128 + k] = (_Float16)W2[j];
        }
    }
    for (int i = t; i < nbkt; i += 256) sh[i] = 0;
    __syncthreads();
    for (long long e = (long long)blockIdx.x * 256 + t; e < E;
         e += (long long)nblocks * 256)
        atomicAdd(&sh[dst[e] >> BKT_SHIFT], 1);
    __syncthreads();
    for (int i = t; i < nbkt; i += 256)
        if (sh[i]) atomicAdd(&bcnt[i], sh[i]);   // device-scope, coherent
    __threadfence();
    __syncthreads();
    __shared__ int last;
    if (t == 0) last = (atomicAdd(&dcnt[0], 1) == nblocks - 1);
    __syncthreads();
    if (!last) return;
    __threadfence();
    // last block: exclusive scan of bcnt[0..nbkt), 4/thread, coherent reads.
    int v[4];
    int s = 0;
    for (int k = 0; k < 4; k++) {
        int idx = t * 4 + k;
        v[k] = (idx < nbkt) ? atomicAdd(&bcnt[idx], 0) : 0;
        s += v[k];
    }
    __syncthreads();
    int x = s;
    sh[t] = x;
    __syncthreads();
    for (int o = 1; o < 256; o <<= 1) {
        int y = (t >= o) ? sh[t - o] : 0;
        __syncthreads();
        x += y;
        sh[t] = x;
        __syncthreads();
    }
    int run = x - s;
    for (int k = 0; k < 4; k++) {
        int idx = t * 4 + k;
        if (idx < nbkt) { bofs[idx] = run; bcur[idx] = run; }
        run += v[k];
    }
    if (t == 0) bofs[nbkt] = E;
}

// ---------------- bulk-reservation bin fill (CH=2048: 782 blocks, 20KB LDS) --
__global__ __launch_bounds__(256) void k_binfill(const int* __restrict__ src,
                                                 const int* __restrict__ dst,
                                                 int* __restrict__ bcur,
                                                 unsigned* __restrict__ recs,
                                                 int E, int nbkt) {
    __shared__ unsigned stage[CH];          // 8 KB
    __shared__ unsigned short stageb[CH];   // 4 KB
    __shared__ int cnt[MAXBKT];             // 4 KB
    __shared__ int base[MAXBKT];            // 4 KB
    const int t = threadIdx.x;
    const long long c0 = (long long)blockIdx.x * CH;

    for (int i = t; i < nbkt; i += 256) cnt[i] = 0;
    __syncthreads();

    for (int k = 0; k < CH / 256; k++) {
        int i = k * 256 + t;
        long long e = c0 + i;
        if (e < E) {
            int d = dst[e];
            int b = d >> BKT_SHIFT;
            stage[i] = ((unsigned)(d & (BKT_NODES - 1)) << 17) | (unsigned)src[e];
            stageb[i] = (unsigned short)b;
            atomicAdd(&cnt[b], 1);
        }
    }
    __syncthreads();

    for (int i = t; i < nbkt; i += 256) {
        int c = cnt[i];
        base[i] = c ? atomicAdd(&bcur[i], c) : 0;
        cnt[i] = 0;
    }
    __syncthreads();

    for (int k = 0; k < CH / 256; k++) {
        int i = k * 256 + t;
        if (c0 + i < E) {
            int b = stageb[i];
            int p = base[b] + atomicAdd(&cnt[b], 1);
            recs[p] = stage[i];
        }
    }
}

// ---------------- fused deg + scan + CSR fill ----------------
__global__ __launch_bounds__(256) void k_fill_all(const unsigned* __restrict__ recs,
                                                  const int* __restrict__ bofs,
                                                  float* __restrict__ dinv,
                                                  int* __restrict__ ofs,
                                                  int* __restrict__ col,
                                                  int n, int E) {
    __shared__ int cnt[BKT_NODES];
    __shared__ int sc[BKT_NODES];
    const int b = blockIdx.x, t = threadIdx.x;
    const int beg = bofs[b], end = bofs[b + 1];

    if (t < BKT_NODES) cnt[t] = 0;
    __syncthreads();
    for (int j = beg + t; j < end; j += 256)
        atomicAdd(&cnt[recs[j] >> 17], 1);
    __syncthreads();

    int v = 0, x = 0;
    if (t < BKT_NODES) { v = cnt[t]; x = v; sc[t] = x; }
    __syncthreads();
    for (int o = 1; o < BKT_NODES; o <<= 1) {
        int y = (t >= o && t < BKT_NODES) ? sc[t - o] : 0;
        __syncthreads();
        if (t < BKT_NODES) { x += y; sc[t] = x; }
        __syncthreads();
    }

    const int d0 = b << BKT_SHIFT;
    if (t < BKT_NODES) {
        int off = beg + x - v;
        int node = d0 + t;
        if (node < n) {
            ofs[node] = off;
            dinv[node] = rsqrtf((float)v + 1.0f);
        }
        cnt[t] = off;   // becomes cur
    }
    if (b == 0 && t == 0) ofs[n] = E;
    __syncthreads();

    for (int j = beg + t; j < end; j += 256) {
        unsigned r = recs[j];
        int p = atomicAdd(&cnt[r >> 17], 1);
        col[p] = (int)(r & 0x1FFFF);
    }
}

// ---------------- MFMA GEMM: ts[N x 128](fp16) = dinv[row] * (in @ W) ------
// A fragments straight from global (read-once); W in LDS (proven load-
// bearing: LDS-free variant cost +19us/gemm, round-9 A/B); 4 blocks/CU.
template <int IN_HALF>
__global__ __launch_bounds__(256, 4) void k_gemm_mfma(const void* __restrict__ inp,
                                                      const _Float16* __restrict__ Wt,
                                                      const float* __restrict__ dinv,
                                                      _Float16* __restrict__ out, int n) {
    __shared__ _Float16 Bl[128][136];  // 34.8 KB
    const int t = threadIdx.x;
    const int row0 = blockIdx.x * 64;

    for (int i = t; i < 128 * 16; i += 256) {
        int r = i >> 4, c8 = i & 15;
        *(half8v*)&Bl[r][c8 * 8] = *(const half8v*)&Wt[r * 128 + c8 * 8];
    }
    __syncthreads();

    const int wave = t >> 6;
    const int lane = t & 63;
    const int m0 = wave * 16;
    const int ml = lane & 15;
    const int quad = lane >> 4;

    int r = row0 + m0 + ml;
    if (r >= n) r = n - 1;   // clamp: OOB rows compute garbage, never stored

    float4v acc[8] = {};
#pragma unroll
    for (int kc = 0; kc < 4; kc++) {
        half8v a;
        if (IN_HALF) {
            a = *(const half8v*)((const _Float16*)inp + (size_t)r * 128 + kc * 32 + quad * 8);
        } else {
            const float* ap = (const float*)inp + (size_t)r * 128 + kc * 32 + quad * 8;
            float4v v0 = *(const float4v*)ap;
            float4v v1 = *(const float4v*)(ap + 4);
#pragma unroll
            for (int k = 0; k < 4; k++) {
                a[k] = (_Float16)v0[k];
                a[4 + k] = (_Float16)v1[k];
            }
        }
#pragma unroll
        for (int nt = 0; nt < 8; nt++) {
            half8v bfr = *(const half8v*)&Bl[nt * 16 + ml][kc * 32 + quad * 8];
            acc[nt] = __builtin_amdgcn_mfma_f32_16x16x32_f16(a, bfr, acc[nt], 0, 0, 0);
        }
    }

    int nr = n - row0;
    if (nr > 64) nr = 64;
#pragma unroll
    for (int reg = 0; reg < 4; reg++) {
        int rr = m0 + quad * 4 + reg;
        if (rr < nr) {
            float dv = dinv[row0 + rr];
#pragma unroll
            for (int nt = 0; nt < 8; nt++)
                out[(size_t)(row0 + rr) * 128 + nt * 16 + ml] =
                    (_Float16)(acc[nt][reg] * dv);
        }
    }
}

// ---------------- CSR aggregation (round-7-proven: 32-lane, unroll x8) ------
template <int OUT_HALF>
__global__ __launch_bounds__(256) void k_agg_csr(const int* __restrict__ ofs,
                                                 const int* __restrict__ col,
                                                 const float* __restrict__ dinv,
                                                 const half4v* __restrict__ ts,
                                                 const float* __restrict__ bias,
                                                 void* __restrict__ outp, int n) {
    int gid = blockIdx.x * 256 + threadIdx.x;
    int row = gid >> 5;
    int lane = gid & 31;
    if (row >= n) return;

    float dd = dinv[row];
    int beg = ofs[row];
    int end = ofs[row + 1];

    half4v sv = ts[(size_t)row * 32 + lane];
    float4 acc = make_float4((float)sv[0], (float)sv[1], (float)sv[2], (float)sv[3]);
    float4 acc2 = make_float4(0.f, 0.f, 0.f, 0.f);

    int j = beg;
    for (; j + 7 < end; j += 8) {
        int s0 = col[j],     s1 = col[j + 1], s2 = col[j + 2], s3 = col[j + 3];
        int s4 = col[j + 4], s5 = col[j + 5], s6 = col[j + 6], s7 = col[j + 7];
        half4v v0 = ts[(size_t)s0 * 32 + lane];
        half4v v1 = ts[(size_t)s1 * 32 + lane];
        half4v v2 = ts[(size_t)s2 * 32 + lane];
        half4v v3 = ts[(size_t)s3 * 32 + lane];
        half4v v4 = ts[(size_t)s4 * 32 + lane];
        half4v v5 = ts[(size_t)s5 * 32 + lane];
        half4v v6 = ts[(size_t)s6 * 32 + lane];
        half4v v7 = ts[(size_t)s7 * 32 + lane];
        acc.x  += (float)v0[0] + (float)v1[0] + (float)v2[0] + (float)v3[0];
        acc.y  += (float)v0[1] + (float)v1[1] + (float)v2[1] + (float)v3[1];
        acc.z  += (float)v0[2] + (float)v1[2] + (float)v2[2] + (float)v3[2];
        acc.w  += (float)v0[3] + (float)v1[3] + (float)v2[3] + (float)v3[3];
        acc2.x += (float)v4[0] + (float)v5[0] + (float)v6[0] + (float)v7[0];
        acc2.y += (float)v4[1] + (float)v5[1] + (float)v6[1] + (float)v7[1];
        acc2.z += (float)v4[2] + (float)v5[2] + (float)v6[2] + (float)v7[2];
        acc2.w += (float)v4[3] + (float)v5[3] + (float)v6[3] + (float)v7[3];
    }
    for (; j + 3 < end; j += 4) {
        int s0 = col[j], s1 = col[j + 1], s2 = col[j + 2], s3 = col[j + 3];
        half4v v0 = ts[(size_t)s0 * 32 + lane];
        half4v v1 = ts[(size_t)s1 * 32 + lane];
        half4v v2 = ts[(size_t)s2 * 32 + lane];
        half4v v3 = ts[(size_t)s3 * 32 + lane];
        acc.x += (float)v0[0] + (float)v1[0] + (float)v2[0] + (float)v3[0];
        acc.y += (float)v0[1] + (float)v1[1] + (float)v2[1] + (float)v3[1];
        acc.z += (float)v0[2] + (float)v1[2] + (float)v2[2] + (float)v3[2];
        acc.w += (float)v0[3] + (float)v1[3] + (float)v2[3] + (float)v3[3];
    }
    for (; j < end; j++) {
        half4v v = ts[(size_t)col[j] * 32 + lane];
        acc.x += (float)v[0];
        acc.y += (float)v[1];
        acc.z += (float)v[2];
        acc.w += (float)v[3];
    }
    acc.x += acc2.x; acc.y += acc2.y; acc.z += acc2.z; acc.w += acc2.w;

    float4 bv = *(const float4*)&bias[lane * 4];
    if (OUT_HALF) {
        half4v hv;
        hv[0] = (_Float16)fmaxf(bv.x + dd * acc.x, 0.f);
        hv[1] = (_Float16)fmaxf(bv.y + dd * acc.y, 0.f);
        hv[2] = (_Float16)fmaxf(bv.z + dd * acc.z, 0.f);
        hv[3] = (_Float16)fmaxf(bv.w + dd * acc.w, 0.f);
        ((half4v*)outp)[(size_t)row * 32 + lane] = hv;
    } else {
        float4 o;
        o.x = bv.x + dd * acc.x;
        o.y = bv.y + dd * acc.y;
        o.z = bv.z + dd * acc.z;
        o.w = bv.w + dd * acc.w;
        *(float4*)&((float*)outp)[(size_t)row * 128 + lane * 4] = o;
    }
}

extern "C" void kernel_launch(void* const* d_in, const int* in_sizes, int n_in,
                              void* d_out, int out_size, void* d_ws, size_t ws_size,
                              hipStream_t stream) {
    const int N = in_sizes[0] / 128;
    const int E = in_sizes[1] / 2;
    const float* x  = (const float*)d_in[0];
    const int*   ei = (const int*)d_in[1];
    const float* W1 = (const float*)d_in[2];
    const float* b1 = (const float*)d_in[3];
    const float* W2 = (const float*)d_in[4];
    const float* b2 = (const float*)d_in[5];

    const int* src = ei;
    const int* dst = ei + E;

    const int NBKT = (N + BKT_NODES - 1) / BKT_NODES;

    // ---- workspace layout ----
    _Float16* t    = (_Float16*)d_ws;            // N*128 (ts, reused per layer)
    _Float16* wt1  = t + (size_t)N * 128;        // 16384
    _Float16* wt2  = wt1 + 16384;                // 16384
    float*    dinv = (float*)(wt2 + 16384);      // N
    int*      ofs  = (int*)(dinv + N);           // N+1
    unsigned* recs = (unsigned*)(ofs + ((N + 2 + 255) & ~255)); // E
    int*      col  = (int*)(recs + E);           // E
    int*      bofs = col + E;                    // NBKT+1
    int*      bcur = bofs + NBKT + 1;            // NBKT
    int*      bcnt = bcur + NBKT;                // NBKT
    int*      dcnt = bcnt + NBKT;                // 2 (done counters)

    // layer-1 hidden (fp16, relu applied) in front half of d_out;
    // final fp32 out overwrites d_out afterwards (h16 dead by then).
    _Float16* h16 = (_Float16*)d_out;
    float*    out = (float*)d_out;

    const int nb_g = (N + 63) / 64;
    const int nb_a = (int)(((long long)N * 32 + 255) / 256);
    const int nb_c = (int)(((long long)E + CH - 1) / CH);

    // ---- build chain (memset + 3 dispatches) ----
    hipMemsetAsync(bcnt, 0, (size_t)(NBKT + 2) * 4, stream);   // bcnt + dcnt
    k_bincount_scan<<<256, 256, 0, stream>>>(dst, W1, W2, wt1, wt2,
                                             bcnt, bofs, bcur, dcnt, E, NBKT, 256);
    k_binfill<<<nb_c, 256, 0, stream>>>(src, dst, bcur, recs, E, NBKT);
    k_fill_all<<<NBKT, 256, 0, stream>>>(recs, bofs, dinv, ofs, col, N, E);

    // ---- layer 1: ts = dinv*(x@W1); h16 = relu(b1 + dinv*(ts[d] + sum ts[col])) ----
    k_gemm_mfma<0><<<nb_g, 256, 0, stream>>>(x, wt1, dinv, t, N);
    k_agg_csr<1><<<nb_a, 256, 0, stream>>>(ofs, col, dinv, (const half4v*)t, b1, h16, N);

    // ---- layer 2: ts = dinv*(h16@W2); out = b2 + dinv*(ts[d] + sum ts[col]) ----
    k_gemm_mfma<1><<<nb_g, 256, 0, stream>>>(h16, wt2, dinv, t, N);
    k_agg_csr<0><<<nb_a, 256, 0, stream>>>(ofs, col, dinv, (const half4v*)t, b2, out, N);
}